// Round 7
// baseline (3276.416 us; speedup 1.0000x reference)
//
#include <hip/hip_runtime.h>
#include <cstdint>

#define TSTEPS 512

// ---------------- Threefry2x32-20, bit-exact vs JAX (verified absmax=0) ----
__device__ __forceinline__ void tfr(uint32_t& x0, uint32_t& x1, int r) {
    x0 += x1;
    x1 = (x1 << r) | (x1 >> (32 - r));
    x1 ^= x0;
}

__device__ __forceinline__ void threefry2x32(uint32_t k0, uint32_t k1,
                                             uint32_t c0, uint32_t c1,
                                             uint32_t& o0, uint32_t& o1) {
    uint32_t k2 = k0 ^ k1 ^ 0x1BD11BDAu;
    uint32_t x0 = c0 + k0, x1 = c1 + k1;
    tfr(x0, x1, 13); tfr(x0, x1, 15); tfr(x0, x1, 26); tfr(x0, x1, 6);
    x0 += k1; x1 += k2 + 1u;
    tfr(x0, x1, 17); tfr(x0, x1, 29); tfr(x0, x1, 16); tfr(x0, x1, 24);
    x0 += k2; x1 += k0 + 2u;
    tfr(x0, x1, 13); tfr(x0, x1, 15); tfr(x0, x1, 26); tfr(x0, x1, 6);
    x0 += k0; x1 += k1 + 3u;
    tfr(x0, x1, 17); tfr(x0, x1, 29); tfr(x0, x1, 16); tfr(x0, x1, 24);
    x0 += k1; x1 += k2 + 4u;
    tfr(x0, x1, 13); tfr(x0, x1, 15); tfr(x0, x1, 26); tfr(x0, x1, 6);
    o0 = x0 + k2; o1 = x1 + k0 + 5u;
}

__global__ void k_keys(uint2* __restrict__ keys) {
    int t = threadIdx.x;
    uint32_t o0, o1;
    threefry2x32(0u, 1u, 0u, (uint32_t)t, o0, o1);
    keys[t] = make_uint2(o0, o1);
}

__global__ __launch_bounds__(256) void k_encode(const float* __restrict__ img,
                                                const uint2* __restrict__ keys,
                                                uint32_t* __restrict__ sxm) {
    int gid = blockIdx.x * 256 + threadIdx.x;
    int t = gid >> 15;
    int n = gid & 32767;
    uint2 k = keys[t];
    uint32_t o0, o1;
    threefry2x32(k.x, k.y, 0u, (uint32_t)n, o0, o1);
    float u = __uint_as_float((o0 >> 9) | 0x3f800000u) - 1.0f;
    float p = (img[n] * 200.0f) * 0.0009765625f;
    unsigned long long bal = __ballot(p > u);
    if ((threadIdx.x & 63) == 0) {
        int word = n >> 5;
        sxm[t * 1024 + word]     = (uint32_t)bal;
        sxm[t * 1024 + word + 1] = (uint32_t)(bal >> 32);
    }
}

// LIF: decays 0.25/0.5 are powers of two, spike in {0,1} -> products exact.
__device__ __forceinline__ void lif(float drive, float& m1, float& m2, float& sp) {
    float r = 1.0f - sp;
    m1 = m1 * 0.25f * r + drive;
    m2 = m2 * 0.25f * r + 0.5f * m1;
    sp = (m2 > 0.3f) ? 1.0f : 0.0f;
}

// LDS dword map (R4 layout, unchanged):
//  [0,15840)      tbl2v float2 [8cg][6ci][5ky][33]  (2 channels per entry)
//  [15840,16830)  tbl1  [6c][5ky][33]
//  [16830,17670)  fw2s  [840]
//  [17670,20870)  s3f   [2][1600] spike floats
//  [20870,21670)  s4f   [2][400]
//  [21670,21910)  s5f   [2][120]
//  [21910,22078)  s6f   [2][84]
//  [22078,22414)  s1m   u32 [2][168] row masks (28 bits)
//  [22414,22606)  s2m   u32 [2][96]  (6*14 used, 14 bits)
#define SMEM_DW 22606
#define SMEM_BYTES (SMEM_DW * 4)

// amdgpu_waves_per_eu(4,4): LDS (90.4 KB, dynamic -> invisible to the
// allocator) limits us to 1 block/CU = 4 waves/EU anyway. Pinning it raises
// the VGPR budget 64 -> 128 so fw3r[50] stays in registers (R6: it spilled,
// WRITE_SIZE 6.3 MB).
__global__ __launch_bounds__(1024)
__attribute__((amdgpu_waves_per_eu(4, 4))) void k_main(
        const float* __restrict__ w1g, const float* __restrict__ w2g,
        const float* __restrict__ w3g, const float* __restrict__ fw1g,
        const float* __restrict__ fw2g, const uint32_t* __restrict__ sxm,
        float* __restrict__ out) {
    extern __shared__ float smem[];
    float2*   tbl2v = (float2*)smem;
    float*    tbl1  = smem + 15840;
    float*    fw2s  = smem + 16830;
    float*    s3f   = smem + 17670;
    float*    s4f   = smem + 20870;
    float*    s5f   = smem + 21670;
    float*    s6f   = smem + 21910;
    uint32_t* s1m   = (uint32_t*)(smem + 22078);
    uint32_t* s2m   = (uint32_t*)(smem + 22414);

    const int tid  = threadIdx.x;
    const int lane = tid & 63;
    const int b    = blockIdx.x;

    // ---- build tables (subset sums, ascending kx -> same add order) ----
    for (int e = tid; e < 960; e += 1024) {
        int c = e / 160, r = e % 160, ky = r >> 5, m = r & 31;
        float v = 0.0f;
        #pragma unroll
        for (int kx = 0; kx < 5; ++kx)
            if ((m >> kx) & 1) v += w1g[c * 25 + ky * 5 + kx];
        tbl1[(c * 5 + ky) * 33 + m] = v;
    }
    for (int e = tid; e < 7680; e += 1024) {
        int cg = e / 960, r = e % 960, ci = r / 160, r2 = r % 160;
        int ky = r2 >> 5, m = r2 & 31;
        float v0 = 0.0f, v1 = 0.0f;
        #pragma unroll
        for (int kx = 0; kx < 5; ++kx)
            if ((m >> kx) & 1) {
                v0 += w2g[((cg * 2) * 6 + ci) * 25 + ky * 5 + kx];
                v1 += w2g[((cg * 2 + 1) * 6 + ci) * 25 + ky * 5 + kx];
            }
        tbl2v[((cg * 6 + ci) * 5 + ky) * 33 + m] = make_float2(v0, v1);
    }
    for (int e = tid; e < 840; e += 1024) fw2s[e] = fw2g[e];
    for (int e = tid; e < 4936; e += 1024) smem[17670 + e] = 0.0f;  // zero comm

    // fc1 weights in registers
    float fw1r[15];
    if (tid < 672) {
        int o = tid >> 3, j = tid & 7;
        #pragma unroll
        for (int i = 0; i < 15; ++i) fw1r[i] = fw1g[o * 120 + j * 15 + i];
    }

    // conv3 weights in registers (loop-invariant; 50 VGPRs, statically
    // indexed after unroll; fits in the 128-VGPR budget at 4 waves/EU)
    float fw3r[50];
    if (tid < 960) {
        const int cc = tid >> 3, j = tid & 7;
        const float2* wp = (const float2*)(w3g + cc * 400 + j * 50);
        #pragma unroll
        for (int i = 0; i < 25; ++i) {
            float2 w = wp[i];
            fw3r[2 * i]     = w.x;
            fw3r[2 * i + 1] = w.y;
        }
    }

    // ---- per-thread LIF states (zero-init == reference state0) ----
    float m1a[6] = {}, m2a[6] = {}, spa[6] = {};
    float m1b0 = 0, m2b0 = 0, spb0 = 0, m1b1 = 0, m2b1 = 0, spb1 = 0;
    float m1c0 = 0, m2c0 = 0, spc0 = 0, m1c1 = 0, m2c1 = 0, spc1 = 0;
    float m1d = 0, m2d = 0, spd = 0;
    float m1e = 0, m2e = 0, spe = 0;
    float m1f = 0, m2f = 0, spf = 0;
    float m1g = 0, m2g = 0, spg = 0, accf = 0.0f;

    uint32_t sx_cur = 0u, sx_nxt = 0u;
    if (tid < 896 && lane < 32) {
        sx_cur = sxm[b * 32 + lane];
        sx_nxt = sxm[1024 + b * 32 + lane];
    }

    __syncthreads();

    // ===== time-skewed pipeline: tick tau, stage s handles timestep tau-s.
    // All stages independent within a tick; ONE barrier per tick.
    #pragma unroll 1
    for (int tau = 0; tau < TSTEPS + 6; ++tau) {
        const int p = tau & 1, q = p ^ 1;
        float*          s3w = s3f + p * 1600;
        const float*    s3r = s3f + q * 1600;
        float*          s4w = s4f + p * 400;
        const float*    s4r = s4f + q * 400;
        float*          s5w = s5f + p * 120;
        const float*    s5r = s5f + q * 120;
        float*          s6w = s6f + p * 84;
        const float*    s6r = s6f + q * 84;
        uint32_t*       s1w = s1m + p * 168;
        const uint32_t* s1r = s1m + q * 168;
        uint32_t*       s2w = s2m + p * 96;
        const uint32_t* s2r = s2m + q * 96;

        // ---- conv1 + LIF1 (t = tau): 896 thr = 28 rows x 32 slots ----
        if (tid < 896) {
            const int y = tid >> 5, x = tid & 31;
            const bool valid = (x < 28);
            float d[6];
            #pragma unroll
            for (int c = 0; c < 6; ++c) d[c] = 0.0f;
            #pragma unroll
            for (int ky = 0; ky < 5; ++ky) {
                uint32_t row = (uint32_t)__shfl((int)sx_cur, y + ky, 64);
                uint32_t mm = (row >> x) & 31u;
                #pragma unroll
                for (int c = 0; c < 6; ++c) d[c] += tbl1[(c * 5 + ky) * 33 + mm];
            }
            #pragma unroll
            for (int c = 0; c < 6; ++c) lif(d[c], m1a[c], m2a[c], spa[c]);
            #pragma unroll
            for (int c = 0; c < 6; ++c) {
                unsigned long long bal = __ballot(valid && (spa[c] > 0.0f));
                if (lane == 0)       s1w[c * 28 + (tid >> 6) * 2]     = (uint32_t)bal;
                else if (lane == 32) s1w[c * 28 + (tid >> 6) * 2 + 1] = (uint32_t)(bal >> 32);
            }
            if (lane < 32) {
                sx_cur = sx_nxt;
                int tt = tau + 2; if (tt > TSTEPS - 1) tt = TSTEPS - 1;
                sx_nxt = sxm[tt * 1024 + b * 32 + lane];
            }
        }

        // ---- pool1 + LIF2 (t = tau-1): 1344 slots; round1 all, round2 high --
        {
            const int c = tid / 224, rem = tid % 224;
            const int yy = rem >> 4, xx = rem & 15;
            const bool valid = (xx < 14);
            uint32_t r0 = s1r[c * 28 + 2 * yy];
            uint32_t r1 = s1r[c * 28 + 2 * yy + 1];
            uint32_t sh = 2u * (uint32_t)xx;
            int cnt = (int)((r0 >> sh) & 1u) + (int)((r0 >> (sh + 1)) & 1u)
                    + (int)((r1 >> sh) & 1u) + (int)((r1 >> (sh + 1)) & 1u);
            lif(0.25f * (float)cnt, m1b0, m2b0, spb0);
            unsigned long long bal = __ballot(valid && (spb0 > 0.0f));
            if ((lane & 15) == 0)
                s2w[tid >> 4] = (uint32_t)((bal >> (lane & 48)) & 0x3FFFull);
        }
        if (tid >= 704) {
            const int slot = tid + 320;
            const int c = slot / 224, rem = slot % 224;
            const int yy = rem >> 4, xx = rem & 15;
            const bool valid = (xx < 14);
            uint32_t r0 = s1r[c * 28 + 2 * yy];
            uint32_t r1 = s1r[c * 28 + 2 * yy + 1];
            uint32_t sh = 2u * (uint32_t)xx;
            int cnt = (int)((r0 >> sh) & 1u) + (int)((r0 >> (sh + 1)) & 1u)
                    + (int)((r1 >> sh) & 1u) + (int)((r1 >> (sh + 1)) & 1u);
            lif(0.25f * (float)cnt, m1b1, m2b1, spb1);
            unsigned long long bal = __ballot(valid && (spb1 > 0.0f));
            if ((lane & 15) == 0)
                s2w[slot >> 4] = (uint32_t)((bal >> (lane & 48)) & 0x3FFFull);
        }

        // ---- conv2 + LIF3 (t = tau-2): 800 thr (tid>=224), 2 channels ----
        if (tid >= 224) {
            const int u = tid - 224;
            const int px = u >> 3, cg = u & 7;
            const int yy = px / 10, xx = px % 10;
            float d0 = 0.0f, d1 = 0.0f;
            #pragma unroll
            for (int ci = 0; ci < 6; ++ci) {
                #pragma unroll
                for (int ky = 0; ky < 5; ++ky) {
                    uint32_t mm = (s2r[ci * 14 + yy + ky] >> xx) & 31u;
                    float2 v = tbl2v[((cg * 6 + ci) * 5 + ky) * 33 + mm];
                    d0 += v.x; d1 += v.y;
                }
            }
            lif(d0, m1c0, m2c0, spc0);
            lif(d1, m1c1, m2c1, spc1);
            s3w[(cg * 2) * 100 + px]     = spc0;
            s3w[(cg * 2 + 1) * 100 + px] = spc1;
        }

        // ---- pool2 + LIF4 (t = tau-3): 400 thr ----
        if (tid < 400) {
            const int c = tid / 25, rem = tid % 25;
            const int yy = rem / 5, xx = rem % 5;
            const float* pp = s3r + c * 100 + yy * 20 + xx * 2;
            float sum = pp[0] + pp[1] + pp[10] + pp[11];
            lif(0.25f * sum, m1d, m2d, spd);
            s4w[tid] = spd;
        }

        // ---- conv3 (120x400 dot) + LIF5 (t = tau-4): 8 lanes per output,
        //      weights from registers (fw3r), spikes from LDS ----
        if (tid < 960) {
            const float2* sp = (const float2*)(s4r + (tid & 7) * 50);
            float sum = 0.0f;
            #pragma unroll
            for (int i = 0; i < 25; ++i) {
                float2 s = sp[i];
                sum = fmaf(fw3r[2 * i + 1], s.y, fmaf(fw3r[2 * i], s.x, sum));
            }
            sum += __shfl_xor(sum, 1, 64);
            sum += __shfl_xor(sum, 2, 64);
            sum += __shfl_xor(sum, 4, 64);
            if ((tid & 7) == 0) { lif(sum, m1e, m2e, spe); s5w[tid >> 3] = spe; }
        }

        // ---- fc1 (84x120) + LIF6 (t = tau-5): 8 lanes per output ----
        if (tid < 672) {
            const int j = tid & 7;
            float sum = 0.0f;
            #pragma unroll
            for (int i = 0; i < 15; ++i) sum = fmaf(fw1r[i], s5r[j * 15 + i], sum);
            sum += __shfl_xor(sum, 1, 64);
            sum += __shfl_xor(sum, 2, 64);
            sum += __shfl_xor(sum, 4, 64);
            if (j == 0) { lif(sum, m1f, m2f, spf); s6w[tid >> 3] = spf; }
        }

        // ---- fc2 (10x84) + LIF7 + acc (t = tau-6): 40 thr ----
        if (tid < 40) {
            const int o = tid >> 2, j = tid & 3;
            float sum = 0.0f;
            #pragma unroll
            for (int i = 0; i < 21; ++i)
                sum = fmaf(fw2s[o * 84 + j * 21 + i], s6r[j * 21 + i], sum);
            sum += __shfl_xor(sum, 1, 64);
            sum += __shfl_xor(sum, 2, 64);
            if (j == 0) { lif(sum, m1g, m2g, spg); accf += spg; }
        }

        __syncthreads();   // the ONLY barrier per tick
    }

    if (tid < 40 && (tid & 3) == 0)
        out[b * 10 + (tid >> 2)] = accf * (1.0f / 512.0f);
}

extern "C" void kernel_launch(void* const* d_in, const int* in_sizes, int n_in,
                              void* d_out, int out_size, void* d_ws, size_t ws_size,
                              hipStream_t stream) {
    const float* img = (const float*)d_in[0];
    const float* w1  = (const float*)d_in[1];
    const float* w2  = (const float*)d_in[2];
    const float* w3  = (const float*)d_in[3];
    const float* fw1 = (const float*)d_in[4];
    const float* fw2 = (const float*)d_in[5];
    float* out = (float*)d_out;

    uint2*    keys = (uint2*)d_ws;
    uint32_t* sxm  = (uint32_t*)((char*)d_ws + 4096);

    k_keys<<<1, 512, 0, stream>>>(keys);
    k_encode<<<(TSTEPS * 32768) / 256, 256, 0, stream>>>(img, keys, sxm);

    (void)hipFuncSetAttribute(reinterpret_cast<const void*>(k_main),
                              hipFuncAttributeMaxDynamicSharedMemorySize,
                              SMEM_BYTES);
    k_main<<<32, 1024, SMEM_BYTES, stream>>>(w1, w2, w3, fw1, fw2, sxm, out);
}

// Round 8
// 1968.770 us; speedup vs baseline: 1.6642x; 1.6642x over previous
//
#include <hip/hip_runtime.h>
#include <cstdint>

#define TSTEPS 512

// ---------------- Threefry2x32-20, bit-exact vs JAX (verified absmax=0) ----
__device__ __forceinline__ void tfr(uint32_t& x0, uint32_t& x1, int r) {
    x0 += x1;
    x1 = (x1 << r) | (x1 >> (32 - r));
    x1 ^= x0;
}

__device__ __forceinline__ void threefry2x32(uint32_t k0, uint32_t k1,
                                             uint32_t c0, uint32_t c1,
                                             uint32_t& o0, uint32_t& o1) {
    uint32_t k2 = k0 ^ k1 ^ 0x1BD11BDAu;
    uint32_t x0 = c0 + k0, x1 = c1 + k1;
    tfr(x0, x1, 13); tfr(x0, x1, 15); tfr(x0, x1, 26); tfr(x0, x1, 6);
    x0 += k1; x1 += k2 + 1u;
    tfr(x0, x1, 17); tfr(x0, x1, 29); tfr(x0, x1, 16); tfr(x0, x1, 24);
    x0 += k2; x1 += k0 + 2u;
    tfr(x0, x1, 13); tfr(x0, x1, 15); tfr(x0, x1, 26); tfr(x0, x1, 6);
    x0 += k0; x1 += k1 + 3u;
    tfr(x0, x1, 17); tfr(x0, x1, 29); tfr(x0, x1, 16); tfr(x0, x1, 24);
    x0 += k1; x1 += k2 + 4u;
    tfr(x0, x1, 13); tfr(x0, x1, 15); tfr(x0, x1, 26); tfr(x0, x1, 6);
    o0 = x0 + k2; o1 = x1 + k0 + 5u;
}

__global__ void k_keys(uint2* __restrict__ keys) {
    int t = threadIdx.x;
    uint32_t o0, o1;
    threefry2x32(0u, 1u, 0u, (uint32_t)t, o0, o1);
    keys[t] = make_uint2(o0, o1);
}

__global__ __launch_bounds__(256) void k_encode(const float* __restrict__ img,
                                                const uint2* __restrict__ keys,
                                                uint32_t* __restrict__ sxm) {
    int gid = blockIdx.x * 256 + threadIdx.x;
    int t = gid >> 15;
    int n = gid & 32767;
    uint2 k = keys[t];
    uint32_t o0, o1;
    threefry2x32(k.x, k.y, 0u, (uint32_t)n, o0, o1);
    float u = __uint_as_float((o0 >> 9) | 0x3f800000u) - 1.0f;
    float p = (img[n] * 200.0f) * 0.0009765625f;
    unsigned long long bal = __ballot(p > u);
    if ((threadIdx.x & 63) == 0) {
        int word = n >> 5;
        sxm[t * 1024 + word]     = (uint32_t)bal;
        sxm[t * 1024 + word + 1] = (uint32_t)(bal >> 32);
    }
}

// LIF: decays 0.25/0.5 are powers of two, spike in {0,1} -> products exact.
__device__ __forceinline__ void lif(float drive, float& m1, float& m2, float& sp) {
    float r = 1.0f - sp;
    m1 = m1 * 0.25f * r + drive;
    m2 = m2 * 0.25f * r + 0.5f * m1;
    sp = (m2 > 0.3f) ? 1.0f : 0.0f;
}

// LDS dword map (2 sub-steps per parity buffer):
//  [0,15840)      tbl2v float2 [8cg][6ci][5ky][33]
//  [15840,16830)  tbl1  [6c][5ky][33]
//  [16830,17670)  fw2s  [840]
//  [17670,24070)  s3f   [2p][2u][1600]
//  [24070,25670)  s4f   [2p][2u][400]
//  [25670,26150)  s5f   [2p][2u][120]
//  [26150,26486)  s6f   [2p][2u][84]
//  [26486,27158)  s1m   u32 [2p][2u][168]
//  [27158,27542)  s2m   u32 [2p][2u][96]
#define SMEM_DW 27542
#define SMEM_BYTES (SMEM_DW * 4)

__global__ __launch_bounds__(1024) void k_main(
        const float* __restrict__ w1g, const float* __restrict__ w2g,
        const float* __restrict__ w3g, const float* __restrict__ fw1g,
        const float* __restrict__ fw2g, const uint32_t* __restrict__ sxm,
        float* __restrict__ out) {
    extern __shared__ float smem[];
    float2*   tbl2v = (float2*)smem;
    float*    tbl1  = smem + 15840;
    float*    fw2s  = smem + 16830;
    float*    s3f   = smem + 17670;
    float*    s4f   = smem + 24070;
    float*    s5f   = smem + 25670;
    float*    s6f   = smem + 26150;
    uint32_t* s1m   = (uint32_t*)(smem + 26486);
    uint32_t* s2m   = (uint32_t*)(smem + 27158);

    const int tid  = threadIdx.x;
    const int lane = tid & 63;
    const int b    = blockIdx.x;

    // ---- build tables (subset sums, ascending kx -> same add order) ----
    for (int e = tid; e < 960; e += 1024) {
        int c = e / 160, r = e % 160, ky = r >> 5, m = r & 31;
        float v = 0.0f;
        #pragma unroll
        for (int kx = 0; kx < 5; ++kx)
            if ((m >> kx) & 1) v += w1g[c * 25 + ky * 5 + kx];
        tbl1[(c * 5 + ky) * 33 + m] = v;
    }
    for (int e = tid; e < 7680; e += 1024) {
        int cg = e / 960, r = e % 960, ci = r / 160, r2 = r % 160;
        int ky = r2 >> 5, m = r2 & 31;
        float v0 = 0.0f, v1 = 0.0f;
        #pragma unroll
        for (int kx = 0; kx < 5; ++kx)
            if ((m >> kx) & 1) {
                v0 += w2g[((cg * 2) * 6 + ci) * 25 + ky * 5 + kx];
                v1 += w2g[((cg * 2 + 1) * 6 + ci) * 25 + ky * 5 + kx];
            }
        tbl2v[((cg * 6 + ci) * 5 + ky) * 33 + m] = make_float2(v0, v1);
    }
    for (int e = tid; e < 840; e += 1024) fw2s[e] = fw2g[e];
    for (int e = tid; e < 9872; e += 1024) smem[17670 + e] = 0.0f;  // zero comm

    // fc1 weights in registers
    float fw1r[15];
    if (tid < 672) {
        int o = tid >> 3, j = tid & 7;
        #pragma unroll
        for (int i = 0; i < 15; ++i) fw1r[i] = fw1g[o * 120 + j * 15 + i];
    }

    // ---- per-thread LIF states (zero-init == reference state0) ----
    float m1a[6] = {}, m2a[6] = {}, spa[6] = {};
    float m1b0 = 0, m2b0 = 0, spb0 = 0, m1b1 = 0, m2b1 = 0, spb1 = 0;
    float m1c0 = 0, m2c0 = 0, spc0 = 0, m1c1 = 0, m2c1 = 0, spc1 = 0;
    float m1d = 0, m2d = 0, spd = 0;
    float m1e = 0, m2e = 0, spe = 0;
    float m1f = 0, m2f = 0, spf = 0;
    float m1g = 0, m2g = 0, spg = 0, accf = 0.0f;

    // sx: lane<32 holds even-t rows, lane>=32 holds odd-t rows (row = lane&31)
    uint32_t sx_cur = 0u, sx_nxt = 0u;
    if (tid < 896) {
        int half = lane >> 5, row = lane & 31;
        sx_cur = sxm[half * 1024 + b * 32 + row];
        sx_nxt = sxm[(half + 2) * 1024 + b * 32 + row];
    }

    __syncthreads();

    // ===== time-skewed pipeline, 2 timesteps per tick:
    // stage s at tick tau handles t = 2(tau-s), 2(tau-s)+1. ONE barrier/tick.
    #pragma unroll 1
    for (int tau = 0; tau < TSTEPS / 2 + 6; ++tau) {
        const int p = tau & 1, q = p ^ 1;
        float*          s3w0 = s3f + p * 3200;
        float*          s3w1 = s3w0 + 1600;
        const float*    s3r0 = s3f + q * 3200;
        const float*    s3r1 = s3r0 + 1600;
        float*          s4w0 = s4f + p * 800;
        float*          s4w1 = s4w0 + 400;
        const float*    s4r0 = s4f + q * 800;
        const float*    s4r1 = s4r0 + 400;
        float*          s5w0 = s5f + p * 240;
        float*          s5w1 = s5w0 + 120;
        const float*    s5r0 = s5f + q * 240;
        const float*    s5r1 = s5r0 + 120;
        float*          s6w0 = s6f + p * 168;
        float*          s6w1 = s6w0 + 84;
        const float*    s6r0 = s6f + q * 168;
        const float*    s6r1 = s6r0 + 84;
        uint32_t*       s1w0 = s1m + p * 336;
        uint32_t*       s1w1 = s1w0 + 168;
        const uint32_t* s1r0 = s1m + q * 336;
        const uint32_t* s1r1 = s1r0 + 168;
        uint32_t*       s2w0 = s2m + p * 192;
        uint32_t*       s2w1 = s2w0 + 96;
        const uint32_t* s2r0 = s2m + q * 192;
        const uint32_t* s2r1 = s2r0 + 96;

        // ---- conv1 + LIF1 (t = 2tau, 2tau+1): 896 thr ----
        if (tid < 896) {
            const int y = tid >> 5, x = tid & 31;
            const bool valid = (x < 28);
            #pragma unroll
            for (int u = 0; u < 2; ++u) {
                uint32_t* s1w = u ? s1w1 : s1w0;
                float d[6];
                #pragma unroll
                for (int c = 0; c < 6; ++c) d[c] = 0.0f;
                #pragma unroll
                for (int ky = 0; ky < 5; ++ky) {
                    uint32_t row = (uint32_t)__shfl((int)sx_cur, u * 32 + y + ky, 64);
                    uint32_t mm = (row >> x) & 31u;
                    #pragma unroll
                    for (int c = 0; c < 6; ++c) d[c] += tbl1[(c * 5 + ky) * 33 + mm];
                }
                #pragma unroll
                for (int c = 0; c < 6; ++c) lif(d[c], m1a[c], m2a[c], spa[c]);
                #pragma unroll
                for (int c = 0; c < 6; ++c) {
                    unsigned long long bal = __ballot(valid && (spa[c] > 0.0f));
                    if (lane == 0)       s1w[c * 28 + (tid >> 6) * 2]     = (uint32_t)bal;
                    else if (lane == 32) s1w[c * 28 + (tid >> 6) * 2 + 1] = (uint32_t)(bal >> 32);
                }
            }
            // rotate prefetch: next tick needs t = 2tau+2, 2tau+3
            sx_cur = sx_nxt;
            int tt = 2 * tau + 4 + (lane >> 5);
            if (tt > TSTEPS - 1) tt = TSTEPS - 1;
            sx_nxt = sxm[tt * 1024 + b * 32 + (lane & 31)];
        }

        // ---- pool1 + LIF2 (t = 2(tau-1)+u): 1344 slots ----
        #pragma unroll
        for (int u = 0; u < 2; ++u) {
            const uint32_t* s1r = u ? s1r1 : s1r0;
            uint32_t*       s2w = u ? s2w1 : s2w0;
            {
                const int c = tid / 224, rem = tid % 224;
                const int yy = rem >> 4, xx = rem & 15;
                const bool valid = (xx < 14);
                uint32_t r0 = s1r[c * 28 + 2 * yy];
                uint32_t r1 = s1r[c * 28 + 2 * yy + 1];
                uint32_t sh = 2u * (uint32_t)xx;
                int cnt = (int)((r0 >> sh) & 1u) + (int)((r0 >> (sh + 1)) & 1u)
                        + (int)((r1 >> sh) & 1u) + (int)((r1 >> (sh + 1)) & 1u);
                lif(0.25f * (float)cnt, m1b0, m2b0, spb0);
                unsigned long long bal = __ballot(valid && (spb0 > 0.0f));
                if ((lane & 15) == 0)
                    s2w[tid >> 4] = (uint32_t)((bal >> (lane & 48)) & 0x3FFFull);
            }
            if (tid >= 704) {
                const int slot = tid + 320;
                const int c = slot / 224, rem = slot % 224;
                const int yy = rem >> 4, xx = rem & 15;
                const bool valid = (xx < 14);
                uint32_t r0 = s1r[c * 28 + 2 * yy];
                uint32_t r1 = s1r[c * 28 + 2 * yy + 1];
                uint32_t sh = 2u * (uint32_t)xx;
                int cnt = (int)((r0 >> sh) & 1u) + (int)((r0 >> (sh + 1)) & 1u)
                        + (int)((r1 >> sh) & 1u) + (int)((r1 >> (sh + 1)) & 1u);
                lif(0.25f * (float)cnt, m1b1, m2b1, spb1);
                unsigned long long bal = __ballot(valid && (spb1 > 0.0f));
                if ((lane & 15) == 0)
                    s2w[slot >> 4] = (uint32_t)((bal >> (lane & 48)) & 0x3FFFull);
            }
        }

        // ---- conv2 + LIF3 (t = 2(tau-2)+u): 800 thr (tid>=224) ----
        if (tid >= 224) {
            const int uu = tid - 224;
            const int px = uu >> 3, cg = uu & 7;
            const int yy = px / 10, xx = px % 10;
            #pragma unroll
            for (int u = 0; u < 2; ++u) {
                const uint32_t* s2r = u ? s2r1 : s2r0;
                float*          s3w = u ? s3w1 : s3w0;
                float d0 = 0.0f, d1 = 0.0f;
                #pragma unroll
                for (int ci = 0; ci < 6; ++ci) {
                    #pragma unroll
                    for (int ky = 0; ky < 5; ++ky) {
                        uint32_t mm = (s2r[ci * 14 + yy + ky] >> xx) & 31u;
                        float2 v = tbl2v[((cg * 6 + ci) * 5 + ky) * 33 + mm];
                        d0 += v.x; d1 += v.y;
                    }
                }
                lif(d0, m1c0, m2c0, spc0);
                lif(d1, m1c1, m2c1, spc1);
                s3w[(cg * 2) * 100 + px]     = spc0;
                s3w[(cg * 2 + 1) * 100 + px] = spc1;
            }
        }

        // ---- pool2 + LIF4 (t = 2(tau-3)+u): 400 thr ----
        if (tid < 400) {
            const int c = tid / 25, rem = tid % 25;
            const int yy = rem / 5, xx = rem % 5;
            #pragma unroll
            for (int u = 0; u < 2; ++u) {
                const float* pp = (u ? s3r1 : s3r0) + c * 100 + yy * 20 + xx * 2;
                float sum = pp[0] + pp[1] + pp[10] + pp[11];
                lif(0.25f * sum, m1d, m2d, spd);
                (u ? s4w1 : s4w0)[tid] = spd;
            }
        }

        // ---- conv3 (120x400 dot) + LIF5 (t = 2(tau-4)+u): 8 lanes/output;
        //      w3 loaded once from L2, reused for both timesteps ----
        if (tid < 960) {
            const int cc = tid >> 3, j = tid & 7;
            const float2* wp  = (const float2*)(w3g + cc * 400 + j * 50);
            const float2* sp0 = (const float2*)(s4r0 + j * 50);
            const float2* sp1 = (const float2*)(s4r1 + j * 50);
            float sum0 = 0.0f, sum1 = 0.0f;
            #pragma unroll
            for (int i = 0; i < 25; ++i) {
                float2 w = wp[i];
                float2 a = sp0[i];
                float2 c2 = sp1[i];
                sum0 = fmaf(w.y, a.y,  fmaf(w.x, a.x,  sum0));
                sum1 = fmaf(w.y, c2.y, fmaf(w.x, c2.x, sum1));
            }
            sum0 += __shfl_xor(sum0, 1, 64);
            sum0 += __shfl_xor(sum0, 2, 64);
            sum0 += __shfl_xor(sum0, 4, 64);
            sum1 += __shfl_xor(sum1, 1, 64);
            sum1 += __shfl_xor(sum1, 2, 64);
            sum1 += __shfl_xor(sum1, 4, 64);
            if (j == 0) {
                lif(sum0, m1e, m2e, spe); s5w0[cc] = spe;
                lif(sum1, m1e, m2e, spe); s5w1[cc] = spe;
            }
        }

        // ---- fc1 (84x120) + LIF6 (t = 2(tau-5)+u): 8 lanes/output ----
        if (tid < 672) {
            const int j = tid & 7;
            #pragma unroll
            for (int u = 0; u < 2; ++u) {
                const float* s5r = u ? s5r1 : s5r0;
                float sum = 0.0f;
                #pragma unroll
                for (int i = 0; i < 15; ++i) sum = fmaf(fw1r[i], s5r[j * 15 + i], sum);
                sum += __shfl_xor(sum, 1, 64);
                sum += __shfl_xor(sum, 2, 64);
                sum += __shfl_xor(sum, 4, 64);
                if (j == 0) { lif(sum, m1f, m2f, spf); (u ? s6w1 : s6w0)[tid >> 3] = spf; }
            }
        }

        // ---- fc2 (10x84) + LIF7 + acc (t = 2(tau-6)+u): 40 thr ----
        if (tid < 40) {
            const int o = tid >> 2, j = tid & 3;
            #pragma unroll
            for (int u = 0; u < 2; ++u) {
                const float* s6r = u ? s6r1 : s6r0;
                float sum = 0.0f;
                #pragma unroll
                for (int i = 0; i < 21; ++i)
                    sum = fmaf(fw2s[o * 84 + j * 21 + i], s6r[j * 21 + i], sum);
                sum += __shfl_xor(sum, 1, 64);
                sum += __shfl_xor(sum, 2, 64);
                if (j == 0) { lif(sum, m1g, m2g, spg); accf += spg; }
            }
        }

        __syncthreads();   // the ONLY barrier per tick
    }

    if (tid < 40 && (tid & 3) == 0)
        out[b * 10 + (tid >> 2)] = accf * (1.0f / 512.0f);
}

extern "C" void kernel_launch(void* const* d_in, const int* in_sizes, int n_in,
                              void* d_out, int out_size, void* d_ws, size_t ws_size,
                              hipStream_t stream) {
    const float* img = (const float*)d_in[0];
    const float* w1  = (const float*)d_in[1];
    const float* w2  = (const float*)d_in[2];
    const float* w3  = (const float*)d_in[3];
    const float* fw1 = (const float*)d_in[4];
    const float* fw2 = (const float*)d_in[5];
    float* out = (float*)d_out;

    uint2*    keys = (uint2*)d_ws;
    uint32_t* sxm  = (uint32_t*)((char*)d_ws + 4096);

    k_keys<<<1, 512, 0, stream>>>(keys);
    k_encode<<<(TSTEPS * 32768) / 256, 256, 0, stream>>>(img, keys, sxm);

    (void)hipFuncSetAttribute(reinterpret_cast<const void*>(k_main),
                              hipFuncAttributeMaxDynamicSharedMemorySize,
                              SMEM_BYTES);
    k_main<<<32, 1024, SMEM_BYTES, stream>>>(w1, w2, w3, fw1, fw2, sxm, out);
}